// Round 3
// baseline (392.809 us; speedup 1.0000x reference)
//
#include <hip/hip_runtime.h>
#include <stdint.h>

typedef unsigned short u16;
typedef __attribute__((ext_vector_type(8))) __bf16 bf16x8;
typedef __attribute__((ext_vector_type(4))) float f32x4;
typedef __attribute__((ext_vector_type(16))) float f32x16;

// ---------- helpers ----------
__device__ __forceinline__ u16 f2bf(float f) {  // RNE fp32 -> bf16
  unsigned int u = __builtin_bit_cast(unsigned int, f);
  u = (u + 0x7FFFu + ((u >> 16) & 1u)) >> 16;
  return (u16)u;
}
__device__ __forceinline__ u16 tern2bf(int s) {
  return s == 0 ? (u16)0 : (s > 0 ? (u16)0x3F80 : (u16)0xBF80);
}

#define GLOAD_LDS16(g, l)                                                          \
  __builtin_amdgcn_global_load_lds((__attribute__((address_space(1))) void*)(g),   \
                                   (__attribute__((address_space(3))) void*)(l),   \
                                   16, 0, 0)

// ---------- problem sizes ----------
#define M_TOK 8192
#define N_OUT 4096
#define K_IN  4096
#define RANK  32

// ---------- ws layout (bytes) ----------
#define WS_XB    0ull                     // x bf16  [8192][4096]
#define WS_WB    67108864ull              // W bf16  [4096][4096]
#define WS_BB    100663296ull             // B bf16  [32][4096]
#define WS_A32   100925440ull             // A' bf16 [4096][32]
#define WS_T32   101187584ull             // T bf16  [8192][32]
#define WS_TPART 101711872ull             // T part  [8][8192][32] f32
#define WS_FLAG  110100480ull             // int flag

// ---------- prep kernels ----------
__global__ void k_convert_x(const float4* __restrict__ x, ushort4* __restrict__ xb, int n4) {
  int stride = gridDim.x * blockDim.x;
  for (int i = blockIdx.x * blockDim.x + threadIdx.x; i < n4; i += stride) {
    float4 v = x[i];
    ushort4 o;
    o.x = f2bf(v.x); o.y = f2bf(v.y); o.z = f2bf(v.z); o.w = f2bf(v.w);
    xb[i] = o;
  }
}

__global__ void k_detect_wtype(const int* __restrict__ w, int* __restrict__ flag) {
  int v = w[threadIdx.x];
  bool ok = (v >= -1 && v <= 1);
  unsigned long long m = __ballot(ok);
  if (threadIdx.x == 0) *flag = (m == ~0ull) ? 1 : 0;
}

__global__ void k_convert_w(const void* __restrict__ wq, const int* __restrict__ flag,
                            ushort4* __restrict__ wb, int n4) {
  int is32 = *flag;
  int stride = gridDim.x * blockDim.x;
  for (int i = blockIdx.x * blockDim.x + threadIdx.x; i < n4; i += stride) {
    int s0, s1, s2, s3;
    if (is32) {
      int4 c = ((const int4*)wq)[i];
      s0 = c.x; s1 = c.y; s2 = c.z; s3 = c.w;
    } else {
      char4 c = ((const char4*)wq)[i];
      s0 = c.x; s1 = c.y; s2 = c.z; s3 = c.w;
    }
    ushort4 o;
    o.x = tern2bf(s0); o.y = tern2bf(s1); o.z = tern2bf(s2); o.w = tern2bf(s3);
    wb[i] = o;
  }
}

__global__ void k_prep_B(const float* __restrict__ loraB, u16* __restrict__ bb) {
  int idx = blockIdx.x * blockDim.x + threadIdx.x;  // 32*4096
  if (idx < RANK * K_IN) bb[idx] = f2bf(loraB[idx]);
}

__global__ void k_prep_A(const float* __restrict__ loraA, const float* __restrict__ scale,
                         u16* __restrict__ a32) {
  int idx = blockIdx.x * blockDim.x + threadIdx.x;  // 4096*32
  if (idx >= N_OUT * RANK) return;
  int o = idx >> 5;
  a32[idx] = f2bf(loraA[idx] / scale[o]);
}

// ---------- T = x @ B^T (partials over 8 K-slices) ----------
__global__ __launch_bounds__(256) void k_lora_T(const u16* __restrict__ xb,
                                                const u16* __restrict__ bb,
                                                float* __restrict__ tpart) {
  __shared__ u16 As[256 * 32];
  __shared__ u16 Bs[32 * 32];
  int mt = blockIdx.x >> 3;
  int ks = blockIdx.x & 7;
  int tid = threadIdx.x, lane = tid & 63, wave = tid >> 6;
  int m0 = mt * 256;
  int kbase0 = ks * 512;
  f32x4 acc[4][2] = {};
  for (int step = 0; step < 16; ++step) {
    int kb = kbase0 + step * 32;
    __syncthreads();
#pragma unroll
    for (int i = 0; i < 4; ++i) {
      const u16* src = xb + (size_t)(m0 + i * 64 + (tid >> 2)) * K_IN + kb + (tid & 3) * 8;
      GLOAD_LDS16(src, &As[i * 2048 + tid * 8]);
    }
    if (tid < 128) {
      const u16* src = bb + (size_t)(tid >> 2) * K_IN + kb + (tid & 3) * 8;
      GLOAD_LDS16(src, &Bs[tid * 8]);
    }
    __syncthreads();
    bf16x8 b[2];
#pragma unroll
    for (int ni = 0; ni < 2; ++ni)
      b[ni] = *(const bf16x8*)&Bs[(ni * 16 + (lane & 15)) * 32 + (lane >> 4) * 8];
#pragma unroll
    for (int mi = 0; mi < 4; ++mi) {
      bf16x8 a = *(const bf16x8*)&As[(wave * 64 + mi * 16 + (lane & 15)) * 32 + (lane >> 4) * 8];
      acc[mi][0] = __builtin_amdgcn_mfma_f32_16x16x32_bf16(a, b[0], acc[mi][0], 0, 0, 0);
      acc[mi][1] = __builtin_amdgcn_mfma_f32_16x16x32_bf16(a, b[1], acc[mi][1], 0, 0, 0);
    }
  }
#pragma unroll
  for (int mi = 0; mi < 4; ++mi)
#pragma unroll
    for (int ni = 0; ni < 2; ++ni)
#pragma unroll
      for (int r = 0; r < 4; ++r) {
        int row = m0 + wave * 64 + mi * 16 + (lane >> 4) * 4 + r;
        int col = ni * 16 + (lane & 15);
        tpart[((size_t)ks * M_TOK + row) * RANK + col] = acc[mi][ni][r];
      }
}

__global__ void k_reduce_T(const float* __restrict__ tpart, u16* __restrict__ t32) {
  int idx = blockIdx.x * blockDim.x + threadIdx.x;  // 8192*32
  if (idx >= M_TOK * RANK) return;
  int t = idx >> 5, r = idx & 31;
  float v = 0.f;
#pragma unroll
  for (int s = 0; s < 8; ++s) v += tpart[((size_t)s * M_TOK + t) * RANK + r];
  t32[idx] = f2bf(v);
}

// ---------- main GEMM: 256x256 tile, BK=32, ring-4 LDS, 32x32x16 MFMA ----------
// 8 waves (2M x 4N), per-wave out 128x64 = acc[4 mb][2 nb] f32x16 frags.
// LDS swizzle identical to R2 (verified 0 conflicts): logical chunk c (16B)
// of row r stored at chunk c ^ ((r>>1)&3); staged via linear gload_lds dest
// with pre-swizzled global source chunk.
// 32x32x16 frags: A row = l&31, k = (l>>5)*8+j; C/D col=l&31,
// row = (reg&3) + 8*(reg>>2) + 4*(l>>5).
__global__ __launch_bounds__(512, 2) void k_gemm8(const u16* __restrict__ xb,
                                                  const u16* __restrict__ wb,
                                                  const u16* __restrict__ t32,
                                                  const u16* __restrict__ a32,
                                                  const float* __restrict__ scale,
                                                  const float* __restrict__ bias,
                                                  float* __restrict__ out) {
  __shared__ u16 As[4][8192];  // 4 slots x 16KB
  __shared__ u16 Bs[4][8192];
  const int tid = threadIdx.x;
  const int l = tid & 63, w = tid >> 6;
  const int wm = w >> 2, wn = w & 3;
  const int bid = blockIdx.x;                    // 512 blocks, 512%8==0
  const int swz = (bid & 7) * 64 + (bid >> 3);   // bijective XCD swizzle
  const int m0 = (swz >> 4) * 256, n0 = (swz & 15) * 256;

  // staging map (same as R2)
  const int srow0 = (w * 2 + 0) * 16 + (l >> 2);
  const int srow1 = (w * 2 + 1) * 16 + (l >> 2);
  const int scx = ((l & 3) ^ ((l >> 3) & 3)) * 8;  // pre-swizzled source chunk (u16)
  const int ldst0 = (w * 2 + 0) * 512 + l * 8;     // u16 index
  const int ldst1 = (w * 2 + 1) * 512 + l * 8;
  // frag-read map: 32-row frags; swizzle XOR depends only on (l&31)>>1 & 3
  const int r31 = l & 31;
  const int kh = l >> 5;                 // k-half within frag (0/1)
  const int swx = (r31 >> 1) & 3;
  const int co0 = ((0 * 2 + kh) ^ swx) * 8;  // ks=0 swizzled chunk offset (u16)
  const int co1 = co0 ^ 16;                  // ks=1 (cb = 2+kh = (kh)^2 under XOR)

  f32x16 acc[4][2] = {};

  auto stageA = [&](int ts) {
    int tc = ts < 128 ? ts : 128;
    const u16 *s0, *s1;
    if (tc < 128) {
      s0 = xb + (size_t)(m0 + srow0) * K_IN + tc * 32 + scx;
      s1 = xb + (size_t)(m0 + srow1) * K_IN + tc * 32 + scx;
    } else {
      s0 = t32 + (size_t)(m0 + srow0) * RANK + scx;
      s1 = t32 + (size_t)(m0 + srow1) * RANK + scx;
    }
    u16* d = &As[ts & 3][0];
    GLOAD_LDS16(s0, d + ldst0);
    GLOAD_LDS16(s1, d + ldst1);
  };
  auto stageB = [&](int ts) {
    int tc = ts < 128 ? ts : 128;
    const u16 *s0, *s1;
    if (tc < 128) {
      s0 = wb + (size_t)(n0 + srow0) * K_IN + tc * 32 + scx;
      s1 = wb + (size_t)(n0 + srow1) * K_IN + tc * 32 + scx;
    } else {
      s0 = a32 + (size_t)(n0 + srow0) * RANK + scx;
      s1 = a32 + (size_t)(n0 + srow1) * RANK + scx;
    }
    u16* d = &Bs[ts & 3][0];
    GLOAD_LDS16(s0, d + ldst0);
    GLOAD_LDS16(s1, d + ldst1);
  };

  // prologue: stage tiles 0,1,2; wait until tile 0 landed (newest 8 = tiles 1,2)
  stageA(0); stageB(0);
  stageA(1); stageB(1);
  stageA(2); stageB(2);
  asm volatile("s_waitcnt vmcnt(8)" ::: "memory");
  __builtin_amdgcn_s_barrier();

  const int arow = (wm * 128 + r31) * 32;  // u16 base of A frag row, mb stride 1024
  const int brow = (wn * 64 + r31) * 32;   // u16 base of B frag row, nb stride 1024

#pragma unroll 1
  for (int t = 0; t < 129; ++t) {
    const u16* Asl = &As[t & 3][0];
    const u16* Bsl = &Bs[t & 3][0];
    // ---- phase 0: ks=0 (K 0..15 of tile)
    bf16x8 a0[4], b0[2];
#pragma unroll
    for (int mb = 0; mb < 4; ++mb) a0[mb] = *(const bf16x8*)&Asl[arow + mb * 1024 + co0];
#pragma unroll
    for (int nb = 0; nb < 2; ++nb) b0[nb] = *(const bf16x8*)&Bsl[brow + nb * 1024 + co0];
    stageA(t + 3);
    __builtin_amdgcn_s_barrier();
    asm volatile("s_waitcnt lgkmcnt(0)" ::: "memory");
    __builtin_amdgcn_s_setprio(1);
#pragma unroll
    for (int mb = 0; mb < 4; ++mb)
#pragma unroll
      for (int nb = 0; nb < 2; ++nb)
        acc[mb][nb] = __builtin_amdgcn_mfma_f32_32x32x16_bf16(a0[mb], b0[nb], acc[mb][nb], 0, 0, 0);
    __builtin_amdgcn_s_setprio(0);
    __builtin_amdgcn_s_barrier();
    // ---- phase 1: ks=1 (K 16..31 of tile)
    bf16x8 a1[4], b1[2];
#pragma unroll
    for (int mb = 0; mb < 4; ++mb) a1[mb] = *(const bf16x8*)&Asl[arow + mb * 1024 + co1];
#pragma unroll
    for (int nb = 0; nb < 2; ++nb) b1[nb] = *(const bf16x8*)&Bsl[brow + nb * 1024 + co1];
    stageB(t + 3);
    asm volatile("s_waitcnt vmcnt(8)" ::: "memory");  // tile t+1 fully landed
    __builtin_amdgcn_s_barrier();
    asm volatile("s_waitcnt lgkmcnt(0)" ::: "memory");
    __builtin_amdgcn_s_setprio(1);
#pragma unroll
    for (int mb = 0; mb < 4; ++mb)
#pragma unroll
      for (int nb = 0; nb < 2; ++nb)
        acc[mb][nb] = __builtin_amdgcn_mfma_f32_32x32x16_bf16(a1[mb], b1[nb], acc[mb][nb], 0, 0, 0);
    __builtin_amdgcn_s_setprio(0);
    __builtin_amdgcn_s_barrier();
  }

  // epilogue: out = acc*scale[col] + bias[col]
  // C/D: col = l&31, row = (reg&3) + 8*(reg>>2) + 4*(l>>5)
#pragma unroll
  for (int nb = 0; nb < 2; ++nb) {
    int col = n0 + wn * 64 + nb * 32 + r31;
    float s = scale[col], bv = bias[col];
#pragma unroll
    for (int mb = 0; mb < 4; ++mb) {
      int rbase = m0 + wm * 128 + mb * 32 + 4 * kh;
#pragma unroll
      for (int reg = 0; reg < 16; ++reg) {
        int row = rbase + (reg & 3) + 8 * (reg >> 2);
        out[(size_t)row * N_OUT + col] = acc[mb][nb][reg] * s + bv;
      }
    }
  }
}

// ---------- launch ----------
extern "C" void kernel_launch(void* const* d_in, const int* in_sizes, int n_in,
                              void* d_out, int out_size, void* d_ws, size_t ws_size,
                              hipStream_t stream) {
  const float* x     = (const float*)d_in[0];
  const void*  wq    = d_in[1];
  const float* scale = (const float*)d_in[2];
  const float* loraA = (const float*)d_in[3];
  const float* loraB = (const float*)d_in[4];
  const float* bias  = (const float*)d_in[5];
  float* out = (float*)d_out;

  char* ws = (char*)d_ws;
  u16*   xb    = (u16*)(ws + WS_XB);
  u16*   wbuf  = (u16*)(ws + WS_WB);
  u16*   bb    = (u16*)(ws + WS_BB);
  u16*   a32   = (u16*)(ws + WS_A32);
  u16*   t32   = (u16*)(ws + WS_T32);
  float* tpart = (float*)(ws + WS_TPART);
  int*   flag  = (int*)(ws + WS_FLAG);

  k_convert_x<<<2048, 256, 0, stream>>>((const float4*)x, (ushort4*)xb, M_TOK * K_IN / 4);
  k_detect_wtype<<<1, 64, 0, stream>>>((const int*)wq, flag);
  k_convert_w<<<2048, 256, 0, stream>>>(wq, flag, (ushort4*)wbuf, N_OUT * K_IN / 4);
  k_prep_B<<<512, 256, 0, stream>>>(loraB, bb);
  k_prep_A<<<512, 256, 0, stream>>>(loraA, scale, a32);
  k_lora_T<<<256, 256, 0, stream>>>(xb, bb, tpart);
  k_reduce_T<<<1024, 256, 0, stream>>>(tpart, t32);
  k_gemm8<<<512, 512, 0, stream>>>(xb, wbuf, t32, a32, scale, bias, out);

  (void)in_sizes; (void)n_in; (void)out_size; (void)ws_size;
}

// Round 4
// 325.817 us; speedup vs baseline: 1.2056x; 1.2056x over previous
//
#include <hip/hip_runtime.h>
#include <stdint.h>

typedef unsigned short u16;
typedef __attribute__((ext_vector_type(8))) __bf16 bf16x8;
typedef __attribute__((ext_vector_type(4))) float f32x4;

// ---------- helpers ----------
__device__ __forceinline__ u16 f2bf(float f) {  // RNE fp32 -> bf16
  unsigned int u = __builtin_bit_cast(unsigned int, f);
  u = (u + 0x7FFFu + ((u >> 16) & 1u)) >> 16;
  return (u16)u;
}
__device__ __forceinline__ u16 tern2bf(int s) {
  return s == 0 ? (u16)0 : (s > 0 ? (u16)0x3F80 : (u16)0xBF80);
}

#define GLOAD_LDS16(g, l)                                                          \
  __builtin_amdgcn_global_load_lds((__attribute__((address_space(1))) void*)(g),   \
                                   (__attribute__((address_space(3))) void*)(l),   \
                                   16, 0, 0)

// ---------- problem sizes ----------
#define M_TOK 8192
#define N_OUT 4096
#define K_IN  4096
#define RANK  32

// ---------- ws layout (bytes) ----------
#define WS_XB    0ull
#define WS_WB    67108864ull
#define WS_BB    100663296ull
#define WS_A32   100925440ull
#define WS_T32   101187584ull
#define WS_TPART 101711872ull
#define WS_FLAG  110100480ull

// ---------- prep kernels ----------
__global__ void k_convert_x(const float4* __restrict__ x, ushort4* __restrict__ xb, int n4) {
  int stride = gridDim.x * blockDim.x;
  for (int i = blockIdx.x * blockDim.x + threadIdx.x; i < n4; i += stride) {
    float4 v = x[i];
    ushort4 o;
    o.x = f2bf(v.x); o.y = f2bf(v.y); o.z = f2bf(v.z); o.w = f2bf(v.w);
    xb[i] = o;
  }
}

__global__ void k_detect_wtype(const int* __restrict__ w, int* __restrict__ flag) {
  int v = w[threadIdx.x];
  bool ok = (v >= -1 && v <= 1);
  unsigned long long m = __ballot(ok);
  if (threadIdx.x == 0) *flag = (m == ~0ull) ? 1 : 0;
}

__global__ void k_convert_w(const void* __restrict__ wq, const int* __restrict__ flag,
                            ushort4* __restrict__ wb, int n4) {
  int is32 = *flag;
  int stride = gridDim.x * blockDim.x;
  for (int i = blockIdx.x * blockDim.x + threadIdx.x; i < n4; i += stride) {
    int s0, s1, s2, s3;
    if (is32) {
      int4 c = ((const int4*)wq)[i];
      s0 = c.x; s1 = c.y; s2 = c.z; s3 = c.w;
    } else {
      char4 c = ((const char4*)wq)[i];
      s0 = c.x; s1 = c.y; s2 = c.z; s3 = c.w;
    }
    ushort4 o;
    o.x = tern2bf(s0); o.y = tern2bf(s1); o.z = tern2bf(s2); o.w = tern2bf(s3);
    wb[i] = o;
  }
}

__global__ void k_prep_B(const float* __restrict__ loraB, u16* __restrict__ bb) {
  int idx = blockIdx.x * blockDim.x + threadIdx.x;
  if (idx < RANK * K_IN) bb[idx] = f2bf(loraB[idx]);
}

__global__ void k_prep_A(const float* __restrict__ loraA, const float* __restrict__ scale,
                         u16* __restrict__ a32) {
  int idx = blockIdx.x * blockDim.x + threadIdx.x;
  if (idx >= N_OUT * RANK) return;
  int o = idx >> 5;
  a32[idx] = f2bf(loraA[idx] / scale[o]);
}

// ---------- T = x @ B^T (partials over 8 K-slices) ----------
__global__ __launch_bounds__(256) void k_lora_T(const u16* __restrict__ xb,
                                                const u16* __restrict__ bb,
                                                float* __restrict__ tpart) {
  __shared__ u16 As[256 * 32];
  __shared__ u16 Bs[32 * 32];
  int mt = blockIdx.x >> 3;
  int ks = blockIdx.x & 7;
  int tid = threadIdx.x, lane = tid & 63, wave = tid >> 6;
  int m0 = mt * 256;
  int kbase0 = ks * 512;
  f32x4 acc[4][2] = {};
  for (int step = 0; step < 16; ++step) {
    int kb = kbase0 + step * 32;
    __syncthreads();
#pragma unroll
    for (int i = 0; i < 4; ++i) {
      const u16* src = xb + (size_t)(m0 + i * 64 + (tid >> 2)) * K_IN + kb + (tid & 3) * 8;
      GLOAD_LDS16(src, &As[i * 2048 + tid * 8]);
    }
    if (tid < 128) {
      const u16* src = bb + (size_t)(tid >> 2) * K_IN + kb + (tid & 3) * 8;
      GLOAD_LDS16(src, &Bs[tid * 8]);
    }
    __syncthreads();
    bf16x8 b[2];
#pragma unroll
    for (int ni = 0; ni < 2; ++ni)
      b[ni] = *(const bf16x8*)&Bs[(ni * 16 + (lane & 15)) * 32 + (lane >> 4) * 8];
#pragma unroll
    for (int mi = 0; mi < 4; ++mi) {
      bf16x8 a = *(const bf16x8*)&As[(wave * 64 + mi * 16 + (lane & 15)) * 32 + (lane >> 4) * 8];
      acc[mi][0] = __builtin_amdgcn_mfma_f32_16x16x32_bf16(a, b[0], acc[mi][0], 0, 0, 0);
      acc[mi][1] = __builtin_amdgcn_mfma_f32_16x16x32_bf16(a, b[1], acc[mi][1], 0, 0, 0);
    }
  }
#pragma unroll
  for (int mi = 0; mi < 4; ++mi)
#pragma unroll
    for (int ni = 0; ni < 2; ++ni)
#pragma unroll
      for (int r = 0; r < 4; ++r) {
        int row = m0 + wave * 64 + mi * 16 + (lane >> 4) * 4 + r;
        int col = ni * 16 + (lane & 15);
        tpart[((size_t)ks * M_TOK + row) * RANK + col] = acc[mi][ni][r];
      }
}

__global__ void k_reduce_T(const float* __restrict__ tpart, u16* __restrict__ t32) {
  int idx = blockIdx.x * blockDim.x + threadIdx.x;
  if (idx >= M_TOK * RANK) return;
  int t = idx >> 5, r = idx & 31;
  float v = 0.f;
#pragma unroll
  for (int s = 0; s < 8; ++s) v += tpart[((size_t)s * M_TOK + t) * RANK + r];
  t32[idx] = f2bf(v);
}

// ---------- main GEMM: 256x256 tile, BK=32, ring-4 LDS, 16x16x32 MFMA ----------
// R2 structure (0 bank conflicts) with: 1 barrier/tile (trailing only), no
// explicit lgkm drains (compiler fine-grains), LoRA tile + tail peeled,
// pure pointer-increment staging in the hot loop (unrolled x4, slots const).
__global__ __launch_bounds__(512, 2) void k_gemm8(const u16* __restrict__ xb,
                                                  const u16* __restrict__ wb,
                                                  const u16* __restrict__ t32,
                                                  const u16* __restrict__ a32,
                                                  const float* __restrict__ scale,
                                                  const float* __restrict__ bias,
                                                  float* __restrict__ out) {
  __shared__ u16 As[4][8192];  // 4 slots x 16KB
  __shared__ u16 Bs[4][8192];
  const int tid = threadIdx.x;
  const int l = tid & 63, w = tid >> 6;
  const int wm = w >> 2, wn = w & 3;
  const int bid = blockIdx.x;
  const int swz = (bid & 7) * 64 + (bid >> 3);
  const int m0 = (swz >> 4) * 256, n0 = (swz & 15) * 256;

  const int srow0 = (w * 2 + 0) * 16 + (l >> 2);
  const int srow1 = (w * 2 + 1) * 16 + (l >> 2);
  const int scx = ((l & 3) ^ ((l >> 3) & 3)) * 8;
  const int ldst0 = (w * 2 + 0) * 512 + l * 8;
  const int ldst1 = (w * 2 + 1) * 512 + l * 8;
  const int r15 = l & 15;
  const int cxr = (((l >> 4) ^ ((r15 >> 1) & 3)) * 8);

  f32x4 acc[8][4] = {};

  u16* AsF = &As[0][0];
  u16* BsF = &Bs[0][0];
  const u16* axs0 = xb + (size_t)(m0 + srow0) * K_IN + scx;
  const u16* axs1 = xb + (size_t)(m0 + srow1) * K_IN + scx;
  const u16* bxs0 = wb + (size_t)(n0 + srow0) * K_IN + scx;
  const u16* bxs1 = wb + (size_t)(n0 + srow1) * K_IN + scx;

  // prologue: stage tiles 0,1,2 (queue order A,A,B,B per tile)
#pragma unroll
  for (int ts = 0; ts < 3; ++ts) {
    GLOAD_LDS16(axs0 + ts * 32, AsF + ts * 8192 + ldst0);
    GLOAD_LDS16(axs1 + ts * 32, AsF + ts * 8192 + ldst1);
    GLOAD_LDS16(bxs0 + ts * 32, BsF + ts * 8192 + ldst0);
    GLOAD_LDS16(bxs1 + ts * 32, BsF + ts * 8192 + ldst1);
  }
  asm volatile("s_waitcnt vmcnt(8)" ::: "memory");
  asm volatile("s_barrier" ::: "memory");

  const int abase = (wm * 128 + r15) * 32 + cxr;
  const int bbase = (wn * 64 + r15) * 32 + cxr;

  // running stage pointers -> tile 3
  const u16* ap0 = axs0 + 96;
  const u16* ap1 = axs1 + 96;
  const u16* bp0 = bxs0 + 96;
  const u16* bp1 = bxs1 + 96;

  // One tile: phase0 {read a0/bfr, STAGE_A, 16 MFMA}, phase1 {read a1, STAGE_B,
  // WAIT, 16 MFMA}, trailing BAR. Slots compile-time via x4 unroll.
#define TILE(SLOT, STAGE_A, STAGE_B, WAIT, BAR)                                     \
  {                                                                                 \
    const u16* Asl = AsF + (SLOT) * 8192;                                           \
    const u16* Bsl = BsF + (SLOT) * 8192;                                           \
    bf16x8 a0[4], bfr[4], a1[4];                                                    \
    _Pragma("unroll") for (int mi = 0; mi < 4; ++mi)                                \
        a0[mi] = *(const bf16x8*)&Asl[abase + mi * 512];                            \
    _Pragma("unroll") for (int nj = 0; nj < 4; ++nj)                                \
        bfr[nj] = *(const bf16x8*)&Bsl[bbase + nj * 512];                           \
    STAGE_A                                                                         \
    __builtin_amdgcn_s_setprio(1);                                                  \
    _Pragma("unroll") for (int mi = 0; mi < 4; ++mi)                                \
    _Pragma("unroll") for (int nj = 0; nj < 4; ++nj)                                \
        acc[mi][nj] =                                                               \
            __builtin_amdgcn_mfma_f32_16x16x32_bf16(a0[mi], bfr[nj], acc[mi][nj], 0, 0, 0); \
    __builtin_amdgcn_s_setprio(0);                                                  \
    _Pragma("unroll") for (int mi = 0; mi < 4; ++mi)                                \
        a1[mi] = *(const bf16x8*)&Asl[abase + 2048 + mi * 512];                     \
    STAGE_B                                                                         \
    WAIT                                                                            \
    __builtin_amdgcn_s_setprio(1);                                                  \
    _Pragma("unroll") for (int mi = 0; mi < 4; ++mi)                                \
    _Pragma("unroll") for (int nj = 0; nj < 4; ++nj)                                \
        acc[4 + mi][nj] =                                                           \
            __builtin_amdgcn_mfma_f32_16x16x32_bf16(a1[mi], bfr[nj], acc[4 + mi][nj], 0, 0, 0); \
    __builtin_amdgcn_s_setprio(0);                                                  \
    BAR                                                                             \
  }

#define SA(DST)                                                                     \
  { GLOAD_LDS16(ap0, AsF + (DST) * 8192 + ldst0);                                   \
    GLOAD_LDS16(ap1, AsF + (DST) * 8192 + ldst1); }
#define SB(DST)                                                                     \
  { GLOAD_LDS16(bp0, BsF + (DST) * 8192 + ldst0);                                   \
    GLOAD_LDS16(bp1, BsF + (DST) * 8192 + ldst1);                                   \
    ap0 += 32; ap1 += 32; bp0 += 32; bp1 += 32; }
#define W8  asm volatile("s_waitcnt vmcnt(8)" ::: "memory");
#define W4  asm volatile("s_waitcnt vmcnt(4)" ::: "memory");
#define W0  asm volatile("s_waitcnt vmcnt(0)" ::: "memory");
#define BARR asm volatile("s_barrier" ::: "memory");

  // main loop: tiles 0..123, staging 3..127
#pragma unroll 1
  for (int t = 0; t < 124; t += 4) {
    TILE(0, SA(3), SB(3), W8, BARR)
    TILE(1, SA(0), SB(0), W8, BARR)
    TILE(2, SA(1), SB(1), W8, BARR)
    TILE(3, SA(2), SB(2), W8, BARR)
  }
  // t=124 (slot 0): stage tile 127 into slot 3
  TILE(0, SA(3), SB(3), W8, BARR)
  // t=125 (slot 1): stage LoRA tile 128 into slot 0
  {
    const u16* la0 = t32 + (size_t)(m0 + srow0) * RANK + scx;
    const u16* la1 = t32 + (size_t)(m0 + srow1) * RANK + scx;
    const u16* lb0 = a32 + (size_t)(n0 + srow0) * RANK + scx;
    const u16* lb1 = a32 + (size_t)(n0 + srow1) * RANK + scx;
    TILE(1,
         { GLOAD_LDS16(la0, AsF + 0 * 8192 + ldst0); GLOAD_LDS16(la1, AsF + 0 * 8192 + ldst1); },
         { GLOAD_LDS16(lb0, BsF + 0 * 8192 + ldst0); GLOAD_LDS16(lb1, BsF + 0 * 8192 + ldst1); },
         W8, BARR)
  }
  // t=126,127 tails; t=128 = LoRA tile in slot 0
  TILE(2, , , W4, BARR)
  TILE(3, , , W0, BARR)
  TILE(0, , , , )

  // epilogue: out = acc*scale[col] + bias[col]
#pragma unroll
  for (int nj = 0; nj < 4; ++nj) {
    int col = n0 + wn * 64 + nj * 16 + r15;
    float s = scale[col], bv = bias[col];
#pragma unroll
    for (int fi = 0; fi < 8; ++fi) {
      int row = m0 + wm * 128 + (fi >> 2) * 64 + (fi & 3) * 16 + (l >> 4) * 4;
#pragma unroll
      for (int r = 0; r < 4; ++r)
        out[(size_t)(row + r) * N_OUT + col] = acc[fi][nj][r] * s + bv;
    }
  }
}

// ---------- launch ----------
extern "C" void kernel_launch(void* const* d_in, const int* in_sizes, int n_in,
                              void* d_out, int out_size, void* d_ws, size_t ws_size,
                              hipStream_t stream) {
  const float* x     = (const float*)d_in[0];
  const void*  wq    = d_in[1];
  const float* scale = (const float*)d_in[2];
  const float* loraA = (const float*)d_in[3];
  const float* loraB = (const float*)d_in[4];
  const float* bias  = (const float*)d_in[5];
  float* out = (float*)d_out;

  char* ws = (char*)d_ws;
  u16*   xb    = (u16*)(ws + WS_XB);
  u16*   wbuf  = (u16*)(ws + WS_WB);
  u16*   bb    = (u16*)(ws + WS_BB);
  u16*   a32   = (u16*)(ws + WS_A32);
  u16*   t32   = (u16*)(ws + WS_T32);
  float* tpart = (float*)(ws + WS_TPART);
  int*   flag  = (int*)(ws + WS_FLAG);

  k_convert_x<<<2048, 256, 0, stream>>>((const float4*)x, (ushort4*)xb, M_TOK * K_IN / 4);
  k_detect_wtype<<<1, 64, 0, stream>>>((const int*)wq, flag);
  k_convert_w<<<2048, 256, 0, stream>>>(wq, flag, (ushort4*)wbuf, N_OUT * K_IN / 4);
  k_prep_B<<<512, 256, 0, stream>>>(loraB, bb);
  k_prep_A<<<512, 256, 0, stream>>>(loraA, scale, a32);
  k_lora_T<<<256, 256, 0, stream>>>(xb, bb, tpart);
  k_reduce_T<<<1024, 256, 0, stream>>>(tpart, t32);
  k_gemm8<<<512, 512, 0, stream>>>(xb, wbuf, t32, a32, scale, bias, out);

  (void)in_sizes; (void)n_in; (void)out_size; (void)ws_size;
}